// Round 19
// baseline (469.984 us; speedup 1.0000x reference)
//
#include <hip/hip_runtime.h>

// LiquidNeuralNetwork: B=512, S=1024, IN=16, HID=64, OUT=1.
// r18 (Picard+MFMA, conflict-free strides, NPIC=2): 285us dispatch, exact.
// Counters: bank-conflict fixed (557K), but Occupancy 23% ~= ONE 512-thr
// block/CU resident (2-3 expected) -> phase stalls amplified.
//
// Round 19:
//  (a) 256-thr blocks (4 waves x 32 sites): standard workgroups co-schedule;
//      combine chain 7->3; barriers sync 4 waves.
//  (b) rank-1 sweep 1: r18's first sweep evaluates G at the frozen guess t0,
//      i.e. 128 IDENTICAL matvecs. Replace with one per-lane broadcast fdot
//      (g0 = Whh_b . t0), register scan seed; delete the eval phase and the
//      Tf init writes (refresh rewrites those rows anyway).
//  (c) 4 barriers/chunk: publish-s1-ends, refresh, publish-s2-ends, h-carry.
// Sweep-2 MFMA eval (own-tile rows; integer self-test gated; VALU fallback)
// and shfl odot kept from r18. Strides: Tf 72 f16, G 68 f32 (<=2-way).

constexpr int HID  = 64;
constexpr int INF  = 16;
constexpr int SLEN = 1024;
constexpr int BATCH = 512;
constexpr int K    = 128;            // chunk steps
constexpr int NS_W = 32;             // sites per wave (4 waves)
constexpr int TFS  = HID + 8;        // Tf row stride (f16): 144 B
constexpr int GS   = HID + 4;        // G row stride (f32): 272 B

typedef __fp16 h2_t   __attribute__((ext_vector_type(2)));
typedef __fp16 f16x8_t __attribute__((ext_vector_type(8)));
typedef float  f32x4_t __attribute__((ext_vector_type(4)));

#if __has_builtin(__builtin_amdgcn_mfma_f32_16x16x32_f16)
#define HAVE_MFMA16 1
#else
#define HAVE_MFMA16 0
#endif

__device__ __forceinline__ float fdot(unsigned a, h2_t w, float acc) {
    return __builtin_amdgcn_fdot2(__builtin_bit_cast(h2_t, a), w, acc, false);
}

__device__ __forceinline__ float fast_tanh(float x) {
    // tanh(x) = 1 - 2/(e^{2x}+1); exact limits at +/-inf, no clamp needed.
    float e = __builtin_amdgcn_exp2f(x * 2.8853900817779268f); // 2*log2(e)
    float r = __builtin_amdgcn_rcpf(e + 1.0f);
    return fmaf(-2.0f, r, 1.0f);
}

// -expm1(-z) by series, exact to ~1e-17 for z ~ 1e-3 (avoids 1-exp cancel)
__device__ __forceinline__ float beta_of(float z) {
    return z * (1.0f - z * (0.5f - z * ((1.0f/6.0f) - z * (1.0f/24.0f))));
}

__global__ __launch_bounds__(256) void lnn_picard3_kernel(
    const float* __restrict__ x,
    const float* __restrict__ W_in,
    const float* __restrict__ b_in,
    const float* __restrict__ W_hh,
    const float* __restrict__ W_ih,
    const float* __restrict__ bias,
    const float* __restrict__ tau,
    const float* __restrict__ W_out,
    const float* __restrict__ b_out,
    float* __restrict__ out)
{
    const int tid  = threadIdx.x;
    const int lane = tid & 63;           // hidden index
    const int wid  = tid >> 6;           // wave id 0..3 (32-site tile each)
    const int b    = blockIdx.x;         // batch index
    const int kg   = lane >> 4;          // k-group 0..3
    const int ln   = lane & 15;          // sub-index 0..15
    const int jb   = NS_W * wid;         // tile base row

    __shared__ __fp16 Tf[K][TFS];        // 18 KB: f16 tanh of trajectory
    __shared__ float  G [K][GS];         // 34 KB: scan/eval scratch
    __shared__ float  hcar[HID];         // chunk-final h carry

    // --- per-lane setup -----------------------------------------------------
    float Wc[INF];
    #pragma unroll
    for (int k = 0; k < INF; ++k) Wc[k] = 0.0f;
    float bcomb = 0.0f;
    for (int j = 0; j < HID; ++j) {
        float wij = W_ih[lane * HID + j];
        bcomb = fmaf(wij, b_in[j], bcomb);
        #pragma unroll
        for (int k = 0; k < INF; ++k) Wc[k] = fmaf(wij, W_in[j * INF + k], Wc[k]);
    }
    const float cbase = bcomb + bias[lane];
    const float bo    = b_out[0];
    const float wo    = W_out[lane];

    const float hsub  = 1.0f / 1023.0f;
    const float rtau  = 1.0f / tau[lane];
    const float beta  = beta_of(hsub * rtau);    // 1 - e^{-dt/tau}
    const float alpha = 1.0f - beta;             // e^{-dt/tau}
    float aa2 = alpha * alpha, aa4 = aa2 * aa2, aa8 = aa4 * aa4;
    float aa16 = aa8 * aa8;
    const float a32 = aa16 * aa16;               // tile propagator (32 steps)

    // wh: lane's own beta-folded row (used by g0 eval AND the VALU fallback)
    h2_t wh[HID / 2];
    {
        const float4* w4 = (const float4*)(W_hh + lane * HID);
        #pragma unroll
        for (int q = 0; q < HID / 4; ++q) {
            float4 v = w4[q];
            wh[2*q+0] = __builtin_amdgcn_cvt_pkrtz(v.x * beta, v.y * beta);
            wh[2*q+1] = __builtin_amdgcn_cvt_pkrtz(v.z * beta, v.w * beta);
        }
    }

    // --- MFMA path: fragments + end-to-end integer self-test ---------------
    bool mfok = false;
#if HAVE_MFMA16
    f16x8_t Bw[4][2];                    // B frags: [col-tile c][k-chunk kc]
    {
        #pragma unroll
        for (int m = 0; m < NS_W; ++m) {
            int j = jb + m;
            Tf[j][lane] = (__fp16)(float)(((j * 5 + lane * 3) & 7) - 3);
        }
        #pragma unroll
        for (int c = 0; c < 4; ++c)
            #pragma unroll
            for (int kc = 0; kc < 2; ++kc) {
                int col = 16 * c + ln;
                #pragma unroll
                for (int e = 0; e < 8; ++e) {
                    int m = 32 * kc + 8 * kg + e;    // slot->k map
                    Bw[c][kc][e] = (__fp16)(float)(((col * 3 + m * 7) & 7) - 3);
                }
            }
        __syncthreads();
        // eval (production code): two 16-row groups per tile
        #pragma unroll
        for (int rg = 0; rg < 2; ++rg) {
            f32x4_t acc[4];
            #pragma unroll
            for (int c = 0; c < 4; ++c) acc[c] = (f32x4_t){0.f, 0.f, 0.f, 0.f};
            const uint4* rowp = (const uint4*)(&Tf[jb + 16 * rg + ln][0]);
            #pragma unroll
            for (int kc = 0; kc < 2; ++kc) {
                f16x8_t A = __builtin_bit_cast(f16x8_t, rowp[4 * kc + kg]);
                #pragma unroll
                for (int c = 0; c < 4; ++c)
                    acc[c] = __builtin_amdgcn_mfma_f32_16x16x32_f16(
                        A, Bw[c][kc], acc[c], 0, 0, 0);
            }
            #pragma unroll
            for (int c = 0; c < 4; ++c)
                #pragma unroll
                for (int r = 0; r < 4; ++r)
                    G[jb + 16 * rg + 4 * kg + r][16 * c + ln] = acc[c][r];
        }
        int ok = 1;
        for (int m = 0; m < NS_W; ++m) {
            int j = jb + m;
            int ref = 0;
            for (int mm = 0; mm < HID; ++mm)
                ref += (((lane * 3 + mm * 7) & 7) - 3)
                     * (((j * 5 + mm * 3) & 7) - 3);
            ok &= (G[j][lane] == (float)ref);
        }
        mfok = (__syncthreads_and(ok) != 0);
        if (mfok) {
            #pragma unroll
            for (int c = 0; c < 4; ++c) {
                int col = 16 * c + ln;
                float bcol = beta_of(hsub * (1.0f / tau[col]));
                #pragma unroll
                for (int kc = 0; kc < 2; ++kc)
                    #pragma unroll
                    for (int e = 0; e < 8; ++e) {
                        int m = 32 * kc + 8 * kg + e;
                        Bw[c][kc][e] = (__fp16)(W_hh[col * HID + m] * bcol);
                    }
            }
        }
    }
#endif

    if (tid == 0) out[(size_t)b * SLEN] = bo;    // step 0: dt=0, h=0

    float h0 = 0.0f;                     // h at chunk start (all lanes/waves)
    float cbreg[NS_W];                   // tile's beta*c in VGPRs

    for (int ch = 0; ch < (SLEN - 1 + K - 1) / K; ++ch) {
        const int sbase = ch * K + 1;
        const int ns    = min(K, (SLEN - 1) - ch * K);   // 128 (last: 127)

        // --- proj (regs) + own t0 row -------------------------------------
        {
            #pragma unroll
            for (int m = 0; m < NS_W; ++m) {
                int j = jb + m;
                if (j < ns) {
                    const float4* xs =
                        (const float4*)(x + ((size_t)b * SLEN + sbase + j) * INF);
                    float4 p0 = xs[0], p1 = xs[1], p2 = xs[2], p3 = xs[3];
                    float cA = fmaf(p0.x, Wc[0], fmaf(p0.y, Wc[1],
                               fmaf(p0.z, Wc[2], fmaf(p0.w, Wc[3], cbase))));
                    float cB = fmaf(p1.x, Wc[4], fmaf(p1.y, Wc[5],
                               fmaf(p1.z, Wc[6], p1.w * Wc[7])));
                    float cC = fmaf(p2.x, Wc[8], fmaf(p2.y, Wc[9],
                               fmaf(p2.z, Wc[10], p2.w * Wc[11])));
                    float cD = fmaf(p3.x, Wc[12], fmaf(p3.y, Wc[13],
                               fmaf(p3.z, Wc[14], p3.w * Wc[15])));
                    cbreg[m] = ((cA + cB) + (cC + cD)) * beta;
                }
            }
            Tf[jb][lane] = (__fp16)fast_tanh(h0);        // own t0 row
        }

        // --- sweep 1 (rank-1): g0 = Whh_b . t0, register scan --------------
        {
            const uint4* t4 = (const uint4*)Tf[jb];      // own row (wave-local)
            float a0 = 0.f, a1 = 0.f, a2_ = 0.f, a3 = 0.f;
            #pragma unroll
            for (int q = 0; q < 8; ++q) {
                uint4 r = t4[q];
                a0  = fdot(r.x, wh[4*q+0], a0);
                a1  = fdot(r.y, wh[4*q+1], a1);
                a2_ = fdot(r.z, wh[4*q+2], a2_);
                a3  = fdot(r.w, wh[4*q+3], a3);
            }
            float g0 = (a0 + a1) + (a2_ + a3);
            float L = 0.0f;
            #pragma unroll
            for (int m = 0; m < NS_W; ++m) {
                int j = jb + m;
                if (j < ns) {
                    L = fmaf(alpha, L, g0 + cbreg[m]);
                    G[j][lane] = L;                      // publish partials
                }
            }
        }
        __syncthreads();                                 // B1: sweep-1 ends

        // --- sweep-1 combine + fixup + Tf refresh --------------------------
        {
            float E = h0;
            for (int w = 0; w < wid; ++w)
                E = fmaf(a32, E, G[NS_W * w + NS_W - 1][lane]);
            float p = alpha;
            #pragma unroll
            for (int m = 0; m < NS_W; ++m) {
                int j = jb + m;
                if (j < ns) {
                    float H = fmaf(p, E, G[j][lane]);
                    if (j + 1 < ns)
                        Tf[j + 1][lane] = (__fp16)fast_tanh(H);
                }
                p *= alpha;
            }
        }
        __syncthreads();                                 // B2: Tf refreshed

        // --- sweep 2: full eval + scan -------------------------------------
#if HAVE_MFMA16
        if (mfok) {
            #pragma unroll
            for (int rg = 0; rg < 2; ++rg) {
                f32x4_t acc[4];
                #pragma unroll
                for (int c = 0; c < 4; ++c) acc[c] = (f32x4_t){0.f,0.f,0.f,0.f};
                const uint4* rowp = (const uint4*)(&Tf[jb + 16 * rg + ln][0]);
                #pragma unroll
                for (int kc = 0; kc < 2; ++kc) {
                    f16x8_t A = __builtin_bit_cast(f16x8_t, rowp[4 * kc + kg]);
                    #pragma unroll
                    for (int c = 0; c < 4; ++c)
                        acc[c] = __builtin_amdgcn_mfma_f32_16x16x32_f16(
                            A, Bw[c][kc], acc[c], 0, 0, 0);
                }
                #pragma unroll
                for (int c = 0; c < 4; ++c)
                    #pragma unroll
                    for (int r = 0; r < 4; ++r)
                        G[jb + 16 * rg + 4 * kg + r][16 * c + ln] = acc[c][r];
            }
        } else
#endif
        {   // VALU eval (r16-proven)
            for (int m = 0; m < NS_W; ++m) {
                int j = jb + m;
                if (j < ns) {
                    const uint4* t4 = (const uint4*)Tf[j];
                    float a0 = 0.f, a1 = 0.f, a2_ = 0.f, a3 = 0.f;
                    #pragma unroll
                    for (int q = 0; q < 8; ++q) {
                        uint4 r = t4[q];
                        a0  = fdot(r.x, wh[4*q+0], a0);
                        a1  = fdot(r.y, wh[4*q+1], a1);
                        a2_ = fdot(r.z, wh[4*q+2], a2_);
                        a3  = fdot(r.w, wh[4*q+3], a3);
                    }
                    G[j][lane] = (a0 + a1) + (a2_ + a3);
                }
            }
        }
        // local scan (same-wave LDS dep only -> no barrier)
        {
            float L = 0.0f;
            #pragma unroll
            for (int m = 0; m < NS_W; ++m) {
                int j = jb + m;
                if (j < ns) {
                    L = fmaf(alpha, L, G[j][lane] + cbreg[m]);
                    G[j][lane] = L;
                }
            }
        }
        __syncthreads();                                 // B3: sweep-2 ends

        // --- sweep-2 combine + fixup + odot + h carry ----------------------
        {
            float E = h0;
            for (int w = 0; w < wid; ++w)
                E = fmaf(a32, E, G[NS_W * w + NS_W - 1][lane]);
            float p = alpha;
            #pragma unroll
            for (int m = 0; m < NS_W; ++m) {
                int j = jb + m;
                if (j < ns) {
                    float H = fmaf(p, E, G[j][lane]);
                    float t = (float)(__fp16)fast_tanh(H);
                    float v = t * wo;
                    #pragma unroll
                    for (int mm = 32; mm >= 1; mm >>= 1)
                        v += __shfl_xor(v, mm, 64);
                    if (lane == 0) out[(size_t)b * SLEN + sbase + j] = v + bo;
                    if (j == ns - 1) hcar[lane] = H;
                }
                p *= alpha;
            }
        }
        __syncthreads();                                 // B4: h carry
        h0 = hcar[lane];
    }
}

extern "C" void kernel_launch(void* const* d_in, const int* in_sizes, int n_in,
                              void* d_out, int out_size, void* d_ws, size_t ws_size,
                              hipStream_t stream) {
    const float* x     = (const float*)d_in[0];
    const float* W_in  = (const float*)d_in[1];
    const float* b_in  = (const float*)d_in[2];
    const float* W_hh  = (const float*)d_in[3];
    const float* W_ih  = (const float*)d_in[4];
    const float* bias  = (const float*)d_in[5];
    const float* tau   = (const float*)d_in[6];
    const float* W_out = (const float*)d_in[7];
    const float* b_out = (const float*)d_in[8];
    float* out = (float*)d_out;

    lnn_picard3_kernel<<<BATCH, 256, 0, stream>>>(
        x, W_in, b_in, W_hh, W_ih, bias, tau, W_out, b_out, out);
}

// Round 20
// 321.639 us; speedup vs baseline: 1.4612x; 1.4612x over previous
//
#include <hip/hip_runtime.h>

// LiquidNeuralNetwork: B=512, S=1024, IN=16, HID=64, OUT=1.
// r18 (Picard+MFMA, 512thr, 8 waves x 16 sites, conflict-free strides,
// NPIC=2): 285us dispatch -- session best. r19 (256thr + rank-1 sweep1)
// regressed to 444us: occupancy halved (1 block/CU regardless of size ->
// waves/CU is what matters), VGPR 136. BUT rank-1 sweep-1 itself passed
// (absmax unchanged) -- the math is hardware-verified.
//
// Round 20 = r18 chassis + rank-1 sweep-1 only:
//  - sweep 1: all 128 sites share the frozen guess t0 -> ONE per-lane
//    broadcast fdot (g0 = Whh_b . t0) + 16-step register scan per tile;
//    deletes a full MFMA eval + G-store phase + 1 barrier per chunk.
//  - sweep 2: unchanged r18 MFMA eval (integer self-test gated, VALU
//    fallback) + local scan + combine; odot fused into the combine
//    (H in registers; saves 16 G round-trips), h0 carried via hcar row.
//  - 4 barriers/chunk. cbreg[16]. Strides: Tf 72 f16, G 68 f32 (<=2-way).

constexpr int HID  = 64;
constexpr int INF  = 16;
constexpr int SLEN = 1024;
constexpr int BATCH = 512;
constexpr int K    = 128;            // chunk steps
constexpr int TFS  = HID + 8;        // Tf row stride (f16): 144 B
constexpr int GS   = HID + 4;        // G row stride (f32): 272 B

typedef __fp16 h2_t   __attribute__((ext_vector_type(2)));
typedef __fp16 f16x8_t __attribute__((ext_vector_type(8)));
typedef float  f32x4_t __attribute__((ext_vector_type(4)));

#if __has_builtin(__builtin_amdgcn_mfma_f32_16x16x32_f16)
#define HAVE_MFMA16 1
#else
#define HAVE_MFMA16 0
#endif

__device__ __forceinline__ float fdot(unsigned a, h2_t w, float acc) {
    return __builtin_amdgcn_fdot2(__builtin_bit_cast(h2_t, a), w, acc, false);
}

__device__ __forceinline__ float fast_tanh(float x) {
    // tanh(x) = 1 - 2/(e^{2x}+1); exact limits at +/-inf, no clamp needed.
    float e = __builtin_amdgcn_exp2f(x * 2.8853900817779268f); // 2*log2(e)
    float r = __builtin_amdgcn_rcpf(e + 1.0f);
    return fmaf(-2.0f, r, 1.0f);
}

// -expm1(-z) by series, exact to ~1e-17 for z ~ 1e-3 (avoids 1-exp cancel)
__device__ __forceinline__ float beta_of(float z) {
    return z * (1.0f - z * (0.5f - z * ((1.0f/6.0f) - z * (1.0f/24.0f))));
}

__global__ __launch_bounds__(512) void lnn_picard4_kernel(
    const float* __restrict__ x,
    const float* __restrict__ W_in,
    const float* __restrict__ b_in,
    const float* __restrict__ W_hh,
    const float* __restrict__ W_ih,
    const float* __restrict__ bias,
    const float* __restrict__ tau,
    const float* __restrict__ W_out,
    const float* __restrict__ b_out,
    float* __restrict__ out)
{
    const int tid  = threadIdx.x;
    const int lane = tid & 63;           // hidden index
    const int wid  = tid >> 6;           // wave id 0..7 (16-site tile each)
    const int b    = blockIdx.x;         // batch index
    const int kg   = lane >> 4;          // k-group 0..3
    const int ln   = lane & 15;          // sub-index 0..15
    const int jb   = 16 * wid;           // tile base row

    __shared__ __fp16 Tf[K][TFS];        // 18 KB: f16 tanh of trajectory
    __shared__ float  G [K][GS];         // 34 KB: scan/eval scratch
    __shared__ float  hcar[HID];         // chunk-final h carry

    // --- per-lane setup -----------------------------------------------------
    float Wc[INF];
    #pragma unroll
    for (int k = 0; k < INF; ++k) Wc[k] = 0.0f;
    float bcomb = 0.0f;
    for (int j = 0; j < HID; ++j) {
        float wij = W_ih[lane * HID + j];
        bcomb = fmaf(wij, b_in[j], bcomb);
        #pragma unroll
        for (int k = 0; k < INF; ++k) Wc[k] = fmaf(wij, W_in[j * INF + k], Wc[k]);
    }
    const float cbase = bcomb + bias[lane];
    const float bo    = b_out[0];
    const float wo    = W_out[lane];

    const float hsub  = 1.0f / 1023.0f;
    const float rtau  = 1.0f / tau[lane];
    const float beta  = beta_of(hsub * rtau);    // 1 - e^{-dt/tau}
    const float alpha = 1.0f - beta;             // e^{-dt/tau}
    float aa2 = alpha * alpha, aa4 = aa2 * aa2, aa8 = aa4 * aa4;
    const float a16 = aa8 * aa8;                 // 16-step tile propagator

    // wh: lane's own beta-folded row (g0 eval AND the VALU fallback)
    h2_t wh[HID / 2];
    {
        const float4* w4 = (const float4*)(W_hh + lane * HID);
        #pragma unroll
        for (int q = 0; q < HID / 4; ++q) {
            float4 v = w4[q];
            wh[2*q+0] = __builtin_amdgcn_cvt_pkrtz(v.x * beta, v.y * beta);
            wh[2*q+1] = __builtin_amdgcn_cvt_pkrtz(v.z * beta, v.w * beta);
        }
    }

    // --- MFMA path: fragments + end-to-end integer self-test (r18-proven) --
    bool mfok = false;
#if HAVE_MFMA16
    f16x8_t Bw[4][2];                    // B frags: [col-tile c][k-chunk kc]
    {
        #pragma unroll
        for (int m = 0; m < 16; ++m) {
            int j = jb + m;
            Tf[j][lane] = (__fp16)(float)(((j * 5 + lane * 3) & 7) - 3);
        }
        #pragma unroll
        for (int c = 0; c < 4; ++c)
            #pragma unroll
            for (int kc = 0; kc < 2; ++kc) {
                int col = 16 * c + ln;
                #pragma unroll
                for (int e = 0; e < 8; ++e) {
                    int m = 32 * kc + 8 * kg + e;    // slot->k map
                    Bw[c][kc][e] = (__fp16)(float)(((col * 3 + m * 7) & 7) - 3);
                }
            }
        __syncthreads();
        {   // eval (production code): A mirrors the slot->k map
            f32x4_t acc[4];
            #pragma unroll
            for (int c = 0; c < 4; ++c) acc[c] = (f32x4_t){0.f, 0.f, 0.f, 0.f};
            const uint4* rowp = (const uint4*)(&Tf[jb + ln][0]);
            #pragma unroll
            for (int kc = 0; kc < 2; ++kc) {
                f16x8_t A = __builtin_bit_cast(f16x8_t, rowp[4 * kc + kg]);
                #pragma unroll
                for (int c = 0; c < 4; ++c)
                    acc[c] = __builtin_amdgcn_mfma_f32_16x16x32_f16(
                        A, Bw[c][kc], acc[c], 0, 0, 0);
            }
            #pragma unroll
            for (int c = 0; c < 4; ++c)
                #pragma unroll
                for (int r = 0; r < 4; ++r)
                    G[jb + 4 * kg + r][16 * c + ln] = acc[c][r];
        }
        int ok = 1;
        for (int m = 0; m < 16; ++m) {
            int j = jb + m;
            int ref = 0;
            for (int mm = 0; mm < HID; ++mm)
                ref += (((lane * 3 + mm * 7) & 7) - 3)
                     * (((j * 5 + mm * 3) & 7) - 3);
            ok &= (G[j][lane] == (float)ref);
        }
        mfok = (__syncthreads_and(ok) != 0);
        if (mfok) {
            #pragma unroll
            for (int c = 0; c < 4; ++c) {
                int col = 16 * c + ln;
                float bcol = beta_of(hsub * (1.0f / tau[col]));
                #pragma unroll
                for (int kc = 0; kc < 2; ++kc)
                    #pragma unroll
                    for (int e = 0; e < 8; ++e) {
                        int m = 32 * kc + 8 * kg + e;
                        Bw[c][kc][e] = (__fp16)(W_hh[col * HID + m] * bcol);
                    }
            }
        }
    }
#endif

    if (tid == 0) out[(size_t)b * SLEN] = bo;    // step 0: dt=0, h=0

    float h0 = 0.0f;                     // h at chunk start (all lanes/waves)
    float cbreg[16];                     // tile's beta*c in VGPRs

    for (int ch = 0; ch < (SLEN - 1 + K - 1) / K; ++ch) {
        const int sbase = ch * K + 1;
        const int ns    = min(K, (SLEN - 1) - ch * K);   // 128 (last: 127)

        // --- proj (regs) + own t0 row --------------------------------------
        {
            #pragma unroll
            for (int m = 0; m < 16; ++m) {
                int j = jb + m;
                if (j < ns) {
                    const float4* xs =
                        (const float4*)(x + ((size_t)b * SLEN + sbase + j) * INF);
                    float4 p0 = xs[0], p1 = xs[1], p2 = xs[2], p3 = xs[3];
                    float cA = fmaf(p0.x, Wc[0], fmaf(p0.y, Wc[1],
                               fmaf(p0.z, Wc[2], fmaf(p0.w, Wc[3], cbase))));
                    float cB = fmaf(p1.x, Wc[4], fmaf(p1.y, Wc[5],
                               fmaf(p1.z, Wc[6], p1.w * Wc[7])));
                    float cC = fmaf(p2.x, Wc[8], fmaf(p2.y, Wc[9],
                               fmaf(p2.z, Wc[10], p2.w * Wc[11])));
                    float cD = fmaf(p3.x, Wc[12], fmaf(p3.y, Wc[13],
                               fmaf(p3.z, Wc[14], p3.w * Wc[15])));
                    cbreg[m] = ((cA + cB) + (cC + cD)) * beta;
                }
            }
            Tf[jb][lane] = (__fp16)fast_tanh(h0);        // own t0 row
        }

        // --- sweep 1 (rank-1): g0 = Whh_b . t0, register scan --------------
        {
            const uint4* t4 = (const uint4*)Tf[jb];      // own row, same-wave
            float a0 = 0.f, a1 = 0.f, a2_ = 0.f, a3 = 0.f;
            #pragma unroll
            for (int q = 0; q < 8; ++q) {
                uint4 r = t4[q];
                a0  = fdot(r.x, wh[4*q+0], a0);
                a1  = fdot(r.y, wh[4*q+1], a1);
                a2_ = fdot(r.z, wh[4*q+2], a2_);
                a3  = fdot(r.w, wh[4*q+3], a3);
            }
            float g0 = (a0 + a1) + (a2_ + a3);
            float L = 0.0f;
            #pragma unroll
            for (int m = 0; m < 16; ++m) {
                int j = jb + m;
                if (j < ns) {
                    L = fmaf(alpha, L, g0 + cbreg[m]);
                    G[j][lane] = L;                      // publish partials
                }
            }
        }
        __syncthreads();                                 // B1: sweep-1 ends

        // --- sweep-1 combine + fixup + Tf refresh --------------------------
        {
            float E = h0;
            for (int w = 0; w < wid; ++w)
                E = fmaf(a16, E, G[16 * w + 15][lane]);
            float p = alpha;
            #pragma unroll
            for (int m = 0; m < 16; ++m) {
                int j = jb + m;
                if (j < ns) {
                    float H = fmaf(p, E, G[j][lane]);
                    if (j + 1 < ns)
                        Tf[j + 1][lane] = (__fp16)fast_tanh(H);
                }
                p *= alpha;
            }
        }
        __syncthreads();                                 // B2: Tf refreshed

        // --- sweep 2: full eval + local scan -------------------------------
#if HAVE_MFMA16
        if (mfok) {
            f32x4_t acc[4];
            #pragma unroll
            for (int c = 0; c < 4; ++c) acc[c] = (f32x4_t){0.f,0.f,0.f,0.f};
            const uint4* rowp = (const uint4*)(&Tf[jb + ln][0]);
            #pragma unroll
            for (int kc = 0; kc < 2; ++kc) {
                f16x8_t A = __builtin_bit_cast(f16x8_t, rowp[4 * kc + kg]);
                #pragma unroll
                for (int c = 0; c < 4; ++c)
                    acc[c] = __builtin_amdgcn_mfma_f32_16x16x32_f16(
                        A, Bw[c][kc], acc[c], 0, 0, 0);
            }
            #pragma unroll
            for (int c = 0; c < 4; ++c)
                #pragma unroll
                for (int r = 0; r < 4; ++r)
                    G[jb + 4 * kg + r][16 * c + ln] = acc[c][r];
        } else
#endif
        {   // VALU eval (r16-proven)
            for (int m = 0; m < 16; ++m) {
                int j = jb + m;
                if (j < ns) {
                    const uint4* t4 = (const uint4*)Tf[j];
                    float a0 = 0.f, a1 = 0.f, a2_ = 0.f, a3 = 0.f;
                    #pragma unroll
                    for (int q = 0; q < 8; ++q) {
                        uint4 r = t4[q];
                        a0  = fdot(r.x, wh[4*q+0], a0);
                        a1  = fdot(r.y, wh[4*q+1], a1);
                        a2_ = fdot(r.z, wh[4*q+2], a2_);
                        a3  = fdot(r.w, wh[4*q+3], a3);
                    }
                    G[j][lane] = (a0 + a1) + (a2_ + a3);
                }
            }
        }
        // local scan (same-wave LDS dep only -> no barrier; r0 idiom)
        {
            float L = 0.0f;
            #pragma unroll
            for (int m = 0; m < 16; ++m) {
                int j = jb + m;
                if (j < ns) {
                    L = fmaf(alpha, L, G[j][lane] + cbreg[m]);
                    G[j][lane] = L;
                }
            }
        }
        __syncthreads();                                 // B3: sweep-2 ends

        // --- sweep-2 combine + fixup + odot (fused) + h carry --------------
        {
            float E = h0;
            for (int w = 0; w < wid; ++w)
                E = fmaf(a16, E, G[16 * w + 15][lane]);
            float p = alpha;
            #pragma unroll
            for (int m = 0; m < 16; ++m) {
                int j = jb + m;
                if (j < ns) {
                    float H = fmaf(p, E, G[j][lane]);
                    float t = (float)(__fp16)fast_tanh(H);
                    float v = t * wo;
                    #pragma unroll
                    for (int mm = 32; mm >= 1; mm >>= 1)
                        v += __shfl_xor(v, mm, 64);
                    if (lane == 0) out[(size_t)b * SLEN + sbase + j] = v + bo;
                    if (j == ns - 1) hcar[lane] = H;
                }
                p *= alpha;
            }
        }
        __syncthreads();                                 // B4: h carry ready
        h0 = hcar[lane];
    }
}

extern "C" void kernel_launch(void* const* d_in, const int* in_sizes, int n_in,
                              void* d_out, int out_size, void* d_ws, size_t ws_size,
                              hipStream_t stream) {
    const float* x     = (const float*)d_in[0];
    const float* W_in  = (const float*)d_in[1];
    const float* b_in  = (const float*)d_in[2];
    const float* W_hh  = (const float*)d_in[3];
    const float* W_ih  = (const float*)d_in[4];
    const float* bias  = (const float*)d_in[5];
    const float* tau   = (const float*)d_in[6];
    const float* W_out = (const float*)d_in[7];
    const float* b_out = (const float*)d_in[8];
    float* out = (float*)d_out;

    lnn_picard4_kernel<<<BATCH, 512, 0, stream>>>(
        x, W_in, b_in, W_hh, W_ih, bias, tau, W_out, b_out, out);
}